// Round 4
// baseline (208.630 us; speedup 1.0000x reference)
//
#include <hip/hip_runtime.h>

// VQ codebook argmin via bf16x3-split MFMA GEMM + quantized top-2 + fp32 rescore.
//   x_in: [B=16, EMB=64, CODES=16384] f32 ; E: [1024, 64] f32
//   out0: x_out [B,EMB,CODES] f32 = E[argmin] ; out1: indices as f32
// score = dot(x, E_k) - 0.5*||E_k||^2  (argmax == argmin of dist2)
// Scan computes 16384*(score+128) in the MFMA accumulator directly:
//   A = x * 2^14 (exact), C-init = wsh2[n] = 16384*(h[n]+128).
//
// R10: additive-pipes diagnosis — at VGPR=64 the allocator serializes each
// t-iter into [MFMA burst -> wait -> top-2 VALU burst] (R9's prefetch/ILP was
// re-sunk; VGPR stayed 64). Fix: explicit 1-deep pipeline — tile t's MFMAs
// issue, then top-2 consumes tile t-1's acc (named regs aPrev0/aPrev1, rule
// #20). Forces ~24 more live regs (cap 128 via launch_bounds(512,4)) and
// gives top-2 a full MFMA chain of slack to hide under.

#define BB 16
#define EMB 64
#define CODES 16384
#define NT 1024
#define NTILES 64
#define CHUNK 8
#define EPOCHS (NTILES / CHUNK)
#define QPB 256          // queries per block (8 waves x 32)

typedef __attribute__((ext_vector_type(8))) short s16x8;   // 8 bf16 (4 VGPRs)
typedef __attribute__((ext_vector_type(4))) float f32x4;   // MFMA acc
typedef __attribute__((ext_vector_type(4))) int i32x4;
typedef unsigned int u32;

__device__ inline short bf16_hi(float f) { return (short)(__builtin_bit_cast(u32, f) >> 16); }
__device__ inline float hi_part(float f) { return __builtin_bit_cast(float, __builtin_bit_cast(u32, f) & 0xFFFF0000u); }
__device__ inline u32 umax_(u32 a, u32 b) { return a > b ? a : b; }

// Async global->LDS, 16 B/lane; LDS dest = wave-uniform base + lane*16.
__device__ inline void async_copy16(const char* g, char* lds_base_uniform) {
  __builtin_amdgcn_global_load_lds(
      (const __attribute__((address_space(1))) unsigned int*)g,
      (__attribute__((address_space(3))) unsigned int*)(unsigned int)(unsigned long long)lds_base_uniform,
      16, 0, 0);
}

// ws layout:
//   [0, 256K)      : B-fragment table (64 n-tiles x 4096 B)
//   [266240, +4K)  : wsh  = -0.5*||E_n||^2            (epilogue rescore)
//   [270336, +4K)  : wsh2 = 16384*(wsh[n]+128)        (scan C-init)
#define WSE_OFF   0
#define WSH_OFF   266240
#define WSH2_OFF  270336

__global__ __launch_bounds__(256) void vq_prep(const float* __restrict__ E,
                                               char* __restrict__ wsE,
                                               float* __restrict__ wsh,
                                               float* __restrict__ wsh2) {
  const int bid = blockIdx.x, tid = threadIdx.x;
  if (bid < 32) {
    const int gid = bid * 256 + tid;              // 8192 tasks: nt(64) x ks(2) x lane(64)
    const int nt = gid >> 7, ks = (gid >> 6) & 1, lane = gid & 63;
    const int col = lane & 15, quad = lane >> 4;
    const int n = nt * 16 + col;
    const int k0 = ks * 32 + quad * 8;
    const float* ep = E + n * EMB + k0;
    s16x8 hv, lv;
    #pragma unroll
    for (int j = 0; j < 8; ++j) {
      float v = ep[j];
      float hf = hi_part(v);
      hv[j] = bf16_hi(v);
      lv[j] = bf16_hi(v - hf);   // v - hf exact in fp32
    }
    char* base = wsE + ((size_t)nt << 12) + ((size_t)ks << 10) + lane * 16;
    *(i32x4*)(base)        = __builtin_bit_cast(i32x4, hv);
    *(i32x4*)(base + 2048) = __builtin_bit_cast(i32x4, lv);
  } else {
    const int n = (bid - 32) * 256 + tid;
    if (n < NT) {
      const float4* ep = (const float4*)(E + n * EMB);
      float s = 0.f;
      #pragma unroll
      for (int g = 0; g < 16; ++g) { float4 v = ep[g]; s += v.x*v.x + v.y*v.y + v.z*v.z + v.w*v.w; }
      const float h = -0.5f * s;
      wsh[n] = h;
      wsh2[n] = 16384.f * (h + 128.f);
    }
  }
}

// Block = 512 threads (8 waves); wave scans 32 queries; block = 256 queries.
__global__ __launch_bounds__(512, 4) void vq_main(
    const float* __restrict__ x, const float* __restrict__ E,
    const char* __restrict__ wsE, const float* __restrict__ wsh,
    const float* __restrict__ wsh2,
    float* __restrict__ xout, float* __restrict__ iout) {
  __shared__ char smem[2 * CHUNK * 4096 + 4096];   // 64 KB B staging + 4 KB wsh2
  float* lh = (float*)(smem + 2 * CHUNK * 4096);
  const int tid = threadIdx.x;
  const int wave = tid >> 6, lane = tid & 63;
  const int col = lane & 15, quad = lane >> 4;
  const int b = blockIdx.y;
  const int c0 = blockIdx.x * QPB;
  const int cw = c0 + wave * 32;

  // Stage wsh2 -> LDS (1024 floats; 512 thr x 8 B) and kick off epoch-0 staging.
  ((float2*)lh)[tid] = ((const float2*)wsh2)[tid];
  {
    const char* g = wsE + wave * 4096 + lane * 16;   // 8 waves x 4 KB = 32 KB epoch
    char* lb = smem + wave * 4096;                   // wave-uniform base
    async_copy16(g,        lb);
    async_copy16(g + 1024, lb + 1024);
    async_copy16(g + 2048, lb + 2048);
    async_copy16(g + 3072, lb + 3072);
  }

  // A fragments: lane holds A[m=col][k=quad*8+j] per (mt, ks); query scaled 2^14.
  s16x8 ah[2][2], al[2][2];
  #pragma unroll
  for (int mt = 0; mt < 2; ++mt) {
    #pragma unroll
    for (int ks = 0; ks < 2; ++ks) {
      s16x8 hv, lv;
      #pragma unroll
      for (int j = 0; j < 8; ++j) {
        const int e = ks * 32 + quad * 8 + j;
        float v = x[((size_t)b * EMB + e) * CODES + (size_t)(cw + mt * 16 + col)] * 16384.f;
        float hf = hi_part(v);
        hv[j] = bf16_hi(v);
        lv[j] = bf16_hi(v - hf);
      }
      ah[mt][ks] = hv;
      al[mt][ks] = lv;
    }
  }

  // key = (u32)acc << 10 | (1023 - n); larger (1023-n) wins ties => earliest idx.
  u32 k1[2][4], k2[2][4];
  #pragma unroll
  for (int mt = 0; mt < 2; ++mt)
    #pragma unroll
    for (int r = 0; r < 4; ++r) { k1[mt][r] = 0u; k2[mt][r] = 0u; }

  // 1-deep pipeline state: previous tile's summed acc + its inv.
  // Fake tile: aPrev=0 -> key = 0<<10 + invPrev <= 1023, below any real key
  // (real acc >= 16384*96 -> key >= 2^30), so k-state is unaffected.
  f32x4 aPrev0 = (f32x4){0.f, 0.f, 0.f, 0.f};
  f32x4 aPrev1 = (f32x4){0.f, 0.f, 0.f, 0.f};
  u32 invCur = 1023u - (u32)col;
  u32 invPrev = 0u;

  __syncthreads();   // drains epoch-0 staging (vmcnt) + wsh2 LDS

  for (int c = 0; c < EPOCHS; ++c) {
    if (c < EPOCHS - 1) {                          // async-stage next epoch
      const char* g = wsE + (size_t)(c + 1) * (CHUNK * 4096) + wave * 4096 + lane * 16;
      char* lb = smem + ((c + 1) & 1) * (CHUNK * 4096) + wave * 4096;
      async_copy16(g,        lb);
      async_copy16(g + 1024, lb + 1024);
      async_copy16(g + 2048, lb + 2048);
      async_copy16(g + 3072, lb + 3072);
    }

    const char* rb = smem + (c & 1) * (CHUNK * 4096) + lane * 16;
    #pragma unroll
    for (int t = 0; t < CHUNK; ++t) {
      const char* p = rb + t * 4096;
      const s16x8 bh0 = __builtin_bit_cast(s16x8, *(const i32x4*)(p));
      const s16x8 bh1 = __builtin_bit_cast(s16x8, *(const i32x4*)(p + 1024));
      const s16x8 bl0 = __builtin_bit_cast(s16x8, *(const i32x4*)(p + 2048));
      const s16x8 bl1 = __builtin_bit_cast(s16x8, *(const i32x4*)(p + 3072));
      const float ch = lh[(c * CHUNK + t) * 16 + col];
      const f32x4 cq = (f32x4){ch, ch, ch, ch};    // C operand carries offset
      const f32x4 zz = (f32x4){0.f, 0.f, 0.f, 0.f};

      // Issue tile t's MFMAs (two independent chains of 3 per mt).
      f32x4 cA0 = __builtin_amdgcn_mfma_f32_16x16x32_bf16(ah[0][0], bh0, cq, 0, 0, 0);
      f32x4 cB0 = __builtin_amdgcn_mfma_f32_16x16x32_bf16(al[0][1], bh1, zz, 0, 0, 0);
      f32x4 cA1 = __builtin_amdgcn_mfma_f32_16x16x32_bf16(ah[1][0], bh0, cq, 0, 0, 0);
      f32x4 cB1 = __builtin_amdgcn_mfma_f32_16x16x32_bf16(al[1][1], bh1, zz, 0, 0, 0);
      cA0 = __builtin_amdgcn_mfma_f32_16x16x32_bf16(ah[0][1], bh1, cA0, 0, 0, 0);
      cB0 = __builtin_amdgcn_mfma_f32_16x16x32_bf16(ah[0][0], bl0, cB0, 0, 0, 0);
      cA1 = __builtin_amdgcn_mfma_f32_16x16x32_bf16(ah[1][1], bh1, cA1, 0, 0, 0);
      cB1 = __builtin_amdgcn_mfma_f32_16x16x32_bf16(ah[1][0], bl0, cB1, 0, 0, 0);
      cA0 = __builtin_amdgcn_mfma_f32_16x16x32_bf16(al[0][0], bh0, cA0, 0, 0, 0);
      cB0 = __builtin_amdgcn_mfma_f32_16x16x32_bf16(ah[0][1], bl1, cB0, 0, 0, 0);
      cA1 = __builtin_amdgcn_mfma_f32_16x16x32_bf16(al[1][0], bh0, cA1, 0, 0, 0);
      cB1 = __builtin_amdgcn_mfma_f32_16x16x32_bf16(ah[1][1], bl1, cB1, 0, 0, 0);

      // Top-2 on the PREVIOUS tile's acc — no dependency on this tile's MFMAs.
      #pragma unroll
      for (int r = 0; r < 4; ++r) {
        u32 q = (u32)aPrev0[r];                    // v_cvt_u32_f32 (trunc), >= 0
        u32 key = (q << 10) + invPrev;
        u32 k1o = k1[0][r];
        asm("v_med3_u32 %0, %1, %2, %3"
            : "=v"(k2[0][r]) : "v"(key), "v"(k1o), "v"(k2[0][r]));
        k1[0][r] = umax_(key, k1o);
      }
      #pragma unroll
      for (int r = 0; r < 4; ++r) {
        u32 q = (u32)aPrev1[r];
        u32 key = (q << 10) + invPrev;
        u32 k1o = k1[1][r];
        asm("v_med3_u32 %0, %1, %2, %3"
            : "=v"(k2[1][r]) : "v"(key), "v"(k1o), "v"(k2[1][r]));
        k1[1][r] = umax_(key, k1o);
      }

      // Commit tile t as the new "previous".
      aPrev0 = cA0 + cB0;
      aPrev1 = cA1 + cB1;
      invPrev = invCur;
      invCur -= 16u;
    }
    __syncthreads();   // drains next-epoch staging; protects buffer reuse
  }

  // Drain: retire the last tile (tile 63) held in the pipeline registers.
  #pragma unroll
  for (int r = 0; r < 4; ++r) {
    u32 q = (u32)aPrev0[r];
    u32 key = (q << 10) + invPrev;
    u32 k1o = k1[0][r];
    asm("v_med3_u32 %0, %1, %2, %3"
        : "=v"(k2[0][r]) : "v"(key), "v"(k1o), "v"(k2[0][r]));
    k1[0][r] = umax_(key, k1o);
  }
  #pragma unroll
  for (int r = 0; r < 4; ++r) {
    u32 q = (u32)aPrev1[r];
    u32 key = (q << 10) + invPrev;
    u32 k1o = k1[1][r];
    asm("v_med3_u32 %0, %1, %2, %3"
        : "=v"(k2[1][r]) : "v"(key), "v"(k1o), "v"(k2[1][r]));
    k1[1][r] = umax_(key, k1o);
  }

  // Merge top-2 across the 16 col-lanes (xor 1,2,4,8 stays inside quad group).
  uint2* cand = (uint2*)smem;                      // staging LDS now free
  int* idxs = (int*)(smem + 2048);
  #pragma unroll
  for (int mt = 0; mt < 2; ++mt) {
    #pragma unroll
    for (int r = 0; r < 4; ++r) {
      u32 a1 = k1[mt][r], a2 = k2[mt][r];
      #pragma unroll
      for (int m = 1; m <= 8; m <<= 1) {
        u32 r1 = __shfl_xor(a1, m, 64);
        u32 r2 = __shfl_xor(a2, m, 64);
        u32 t = a1 < r1 ? a1 : r1;
        a1 = umax_(a1, r1);
        a2 = umax_(umax_(a2, r2), t);
      }
      // C/D layout: local query = wave*32 + mt*16 + quad*4 + r
      if (col == r) cand[wave * 32 + mt * 16 + quad * 4 + r] = make_uint2(a1, a2);
    }
  }
  __syncthreads();

  // Rescore: all 512 threads; 2 threads/query (one candidate each), exact fp32.
  {
    const int q = tid >> 1, which = tid & 1;
    const u32 K = which ? cand[q].y : cand[q].x;
    const int i = 1023 - (int)(K & 1023u);
    const float* xq = x + (size_t)b * EMB * CODES + (size_t)(c0 + q);
    const float4* ei = (const float4*)(E + i * EMB);
    float d0 = 0, d1 = 0, d2 = 0, d3 = 0;
    #pragma unroll
    for (int g = 0; g < 16; ++g) {
      float4 a = ei[g];
      d0 = fmaf(xq[(size_t)(4 * g + 0) * CODES], a.x, d0);
      d1 = fmaf(xq[(size_t)(4 * g + 1) * CODES], a.y, d1);
      d2 = fmaf(xq[(size_t)(4 * g + 2) * CODES], a.z, d2);
      d3 = fmaf(xq[(size_t)(4 * g + 3) * CODES], a.w, d3);
    }
    const float s = ((d0 + d1) + (d2 + d3)) + wsh[i];
    const float s_o = __shfl_xor(s, 1, 64);
    const int i_o = __shfl_xor(i, 1, 64);
    if (which == 0) {
      // (s,i) = candidate 1; (s_o,i_o) = candidate 2
      const bool take2 = (s_o > s) || (s_o == s && i_o < i);
      const int idx = take2 ? i_o : i;
      idxs[q] = idx;
      iout[(size_t)b * CODES + (size_t)(c0 + q)] = (float)idx;
    }
  }
  __syncthreads();

  // Output fan-out: all 512 threads; thread -> (query = tid&255, e-half = tid>>8).
  {
    const int q = tid & (QPB - 1);
    const int eh = (tid >> 8) * 32;
    const int idx = idxs[q];
    const float* Er = E + idx * EMB + eh;
    float* xo = xout + ((size_t)b * EMB + eh) * CODES + (size_t)(c0 + q);
    #pragma unroll
    for (int e = 0; e < 32; ++e) xo[(size_t)e * CODES] = Er[e];
  }
}

extern "C" void kernel_launch(void* const* d_in, const int* in_sizes, int n_in,
                              void* d_out, int out_size, void* d_ws, size_t ws_size,
                              hipStream_t stream) {
  const float* x = (const float*)d_in[0];   // [16, 64, 16384]
  const float* E = (const float*)d_in[1];   // [1024, 64]
  float* xout = (float*)d_out;
  float* iout = (float*)d_out + (size_t)BB * EMB * CODES;

  char* wsE  = (char*)d_ws + WSE_OFF;
  float* wsh  = (float*)((char*)d_ws + WSH_OFF);
  float* wsh2 = (float*)((char*)d_ws + WSH2_OFF);

  vq_prep<<<36, 256, 0, stream>>>(E, wsE, wsh, wsh2);
  vq_main<<<dim3(CODES / QPB, BB), 512, 0, stream>>>(x, E, wsE, wsh, wsh2, xout, iout);
}

// Round 5
// 207.134 us; speedup vs baseline: 1.0072x; 1.0072x over previous
//
#include <hip/hip_runtime.h>

// VQ codebook argmin via bf16x3-split MFMA GEMM + quantized top-2 + fp32 rescore.
//   x_in: [B=16, EMB=64, CODES=16384] f32 ; E: [1024, 64] f32
//   out0: x_out [B,EMB,CODES] f32 = E[argmin] ; out1: indices as f32
// score = dot(x, E_k) - 0.5*||E_k||^2  (argmax == argmin of dist2)
// Scan computes 16384*(score+128) in the MFMA accumulator directly:
//   A = x * 2^14 (exact), C-init = wsh2[n] = 16384*(h[n]+128).
//
// R11: R9/R10 showed the compiler always finds a 64-reg serial schedule
// ([ds_read -> lgkmcnt(0) -> MFMA -> VALU] per tile) and re-sinks any
// C++-level prefetch/pipeline. Pin it with inline asm (m214 recipe):
// volatile ds_read_b128 blocks (4/tile), counted s_waitcnt lgkmcnt(4) so
// the next tile's reads stay in flight under this tile's MFMAs, and
// sched_barrier(0) after each wait (rule #18: MFMAs otherwise hoist past
// asm waitcnt). ch scalars preloaded per epoch and pinned BEFORE the asm
// region so no compiler lgkmcnt lands inside the pipeline.

#define BB 16
#define EMB 64
#define CODES 16384
#define NT 1024
#define NTILES 64
#define CHUNK 8
#define EPOCHS (NTILES / CHUNK)
#define QPB 256          // queries per block (8 waves x 32)

typedef __attribute__((ext_vector_type(8))) short s16x8;   // 8 bf16 (4 VGPRs)
typedef __attribute__((ext_vector_type(4))) float f32x4;   // MFMA acc
typedef __attribute__((ext_vector_type(4))) int i32x4;
typedef unsigned int u32;

__device__ inline short bf16_hi(float f) { return (short)(__builtin_bit_cast(u32, f) >> 16); }
__device__ inline float hi_part(float f) { return __builtin_bit_cast(float, __builtin_bit_cast(u32, f) & 0xFFFF0000u); }
__device__ inline u32 umax_(u32 a, u32 b) { return a > b ? a : b; }

// Async global->LDS, 16 B/lane; LDS dest = wave-uniform base + lane*16.
__device__ inline void async_copy16(const char* g, char* lds_base_uniform) {
  __builtin_amdgcn_global_load_lds(
      (const __attribute__((address_space(1))) unsigned int*)g,
      (__attribute__((address_space(3))) unsigned int*)(unsigned int)(unsigned long long)lds_base_uniform,
      16, 0, 0);
}

// ws layout:
//   [0, 256K)      : B-fragment table (64 n-tiles x 4096 B)
//   [266240, +4K)  : wsh  = -0.5*||E_n||^2            (epilogue rescore)
//   [270336, +4K)  : wsh2 = 16384*(wsh[n]+128)        (scan C-init)
#define WSE_OFF   0
#define WSH_OFF   266240
#define WSH2_OFF  270336

__global__ __launch_bounds__(256) void vq_prep(const float* __restrict__ E,
                                               char* __restrict__ wsE,
                                               float* __restrict__ wsh,
                                               float* __restrict__ wsh2) {
  const int bid = blockIdx.x, tid = threadIdx.x;
  if (bid < 32) {
    const int gid = bid * 256 + tid;              // 8192 tasks: nt(64) x ks(2) x lane(64)
    const int nt = gid >> 7, ks = (gid >> 6) & 1, lane = gid & 63;
    const int col = lane & 15, quad = lane >> 4;
    const int n = nt * 16 + col;
    const int k0 = ks * 32 + quad * 8;
    const float* ep = E + n * EMB + k0;
    s16x8 hv, lv;
    #pragma unroll
    for (int j = 0; j < 8; ++j) {
      float v = ep[j];
      float hf = hi_part(v);
      hv[j] = bf16_hi(v);
      lv[j] = bf16_hi(v - hf);   // v - hf exact in fp32
    }
    char* base = wsE + ((size_t)nt << 12) + ((size_t)ks << 10) + lane * 16;
    *(i32x4*)(base)        = __builtin_bit_cast(i32x4, hv);
    *(i32x4*)(base + 2048) = __builtin_bit_cast(i32x4, lv);
  } else {
    const int n = (bid - 32) * 256 + tid;
    if (n < NT) {
      const float4* ep = (const float4*)(E + n * EMB);
      float s = 0.f;
      #pragma unroll
      for (int g = 0; g < 16; ++g) { float4 v = ep[g]; s += v.x*v.x + v.y*v.y + v.z*v.z + v.w*v.w; }
      const float h = -0.5f * s;
      wsh[n] = h;
      wsh2[n] = 16384.f * (h + 128.f);
    }
  }
}

// Issue one tile's 4 B-fragment reads (volatile asm: cannot be re-sunk).
#define DS_READ_TILE(d0, d1, d2, d3, base, T)                               \
  asm volatile("ds_read_b128 %0, %4 offset:%c5\n\t"                         \
               "ds_read_b128 %1, %4 offset:%c6\n\t"                         \
               "ds_read_b128 %2, %4 offset:%c7\n\t"                         \
               "ds_read_b128 %3, %4 offset:%c8"                             \
               : "=v"(d0), "=v"(d1), "=v"(d2), "=v"(d3)                     \
               : "v"(base), "i"((T) * 4096), "i"((T) * 4096 + 1024),        \
                 "i"((T) * 4096 + 2048), "i"((T) * 4096 + 3072))

// Counted wait + scheduling fence (rule #18).
#define WAIT_SB(N)                                                          \
  do {                                                                      \
    asm volatile("s_waitcnt lgkmcnt(" #N ")");                              \
    __builtin_amdgcn_sched_barrier(0);                                      \
  } while (0)

#define MFMA16 __builtin_amdgcn_mfma_f32_16x16x32_bf16

// 12 MFMAs for one tile + top-2 on PREVIOUS tile's acc, then commit.
#define TILE_MATH(F0, F1, F2, F3, CH)                                       \
  do {                                                                      \
    const s16x8 bh0 = __builtin_bit_cast(s16x8, F0);                        \
    const s16x8 bh1 = __builtin_bit_cast(s16x8, F1);                        \
    const s16x8 bl0 = __builtin_bit_cast(s16x8, F2);                        \
    const s16x8 bl1 = __builtin_bit_cast(s16x8, F3);                        \
    const f32x4 cq = (f32x4){CH, CH, CH, CH};                               \
    const f32x4 zz = (f32x4){0.f, 0.f, 0.f, 0.f};                           \
    f32x4 cA0 = MFMA16(ah[0][0], bh0, cq, 0, 0, 0);                         \
    f32x4 cB0 = MFMA16(al[0][1], bh1, zz, 0, 0, 0);                         \
    f32x4 cA1 = MFMA16(ah[1][0], bh0, cq, 0, 0, 0);                         \
    f32x4 cB1 = MFMA16(al[1][1], bh1, zz, 0, 0, 0);                         \
    cA0 = MFMA16(ah[0][1], bh1, cA0, 0, 0, 0);                              \
    cB0 = MFMA16(ah[0][0], bl0, cB0, 0, 0, 0);                              \
    cA1 = MFMA16(ah[1][1], bh1, cA1, 0, 0, 0);                              \
    cB1 = MFMA16(ah[1][0], bl0, cB1, 0, 0, 0);                              \
    cA0 = MFMA16(al[0][0], bh0, cA0, 0, 0, 0);                              \
    cB0 = MFMA16(ah[0][1], bl1, cB0, 0, 0, 0);                              \
    cA1 = MFMA16(al[1][0], bh0, cA1, 0, 0, 0);                              \
    cB1 = MFMA16(ah[1][1], bl1, cB1, 0, 0, 0);                              \
    TOP2(aPrev0, 0);                                                        \
    TOP2(aPrev1, 1);                                                        \
    aPrev0 = cA0 + cB0;                                                     \
    aPrev1 = cA1 + cB1;                                                     \
    invPrev = invCur;                                                       \
    invCur -= 16u;                                                          \
  } while (0)

#define TOP2(AV, MT)                                                        \
  do {                                                                      \
    _Pragma("unroll")                                                       \
    for (int r = 0; r < 4; ++r) {                                           \
      u32 q = (u32)AV[r];                  /* v_cvt_u32_f32 (trunc) */      \
      u32 key = (q << 10) + invPrev;                                        \
      u32 k1o = k1[MT][r];                                                  \
      asm("v_med3_u32 %0, %1, %2, %3"                                       \
          : "=v"(k2[MT][r]) : "v"(key), "v"(k1o), "v"(k2[MT][r]));          \
      k1[MT][r] = umax_(key, k1o);                                          \
    }                                                                       \
  } while (0)

// Block = 512 threads (8 waves); wave scans 32 queries; block = 256 queries.
__global__ __launch_bounds__(512, 4) void vq_main(
    const float* __restrict__ x, const float* __restrict__ E,
    const char* __restrict__ wsE, const float* __restrict__ wsh,
    const float* __restrict__ wsh2,
    float* __restrict__ xout, float* __restrict__ iout) {
  __shared__ char smem[2 * CHUNK * 4096 + 4096];   // 64 KB B staging + 4 KB wsh2
  float* lh = (float*)(smem + 2 * CHUNK * 4096);
  const int tid = threadIdx.x;
  const int wave = tid >> 6, lane = tid & 63;
  const int col = lane & 15, quad = lane >> 4;
  const int b = blockIdx.y;
  const int c0 = blockIdx.x * QPB;
  const int cw = c0 + wave * 32;

  // Stage wsh2 -> LDS (1024 floats; 512 thr x 8 B) and kick off epoch-0 staging.
  ((float2*)lh)[tid] = ((const float2*)wsh2)[tid];
  {
    const char* g = wsE + wave * 4096 + lane * 16;   // 8 waves x 4 KB = 32 KB epoch
    char* lb = smem + wave * 4096;                   // wave-uniform base
    async_copy16(g,        lb);
    async_copy16(g + 1024, lb + 1024);
    async_copy16(g + 2048, lb + 2048);
    async_copy16(g + 3072, lb + 3072);
  }

  // A fragments: lane holds A[m=col][k=quad*8+j] per (mt, ks); query scaled 2^14.
  s16x8 ah[2][2], al[2][2];
  #pragma unroll
  for (int mt = 0; mt < 2; ++mt) {
    #pragma unroll
    for (int ks = 0; ks < 2; ++ks) {
      s16x8 hv, lv;
      #pragma unroll
      for (int j = 0; j < 8; ++j) {
        const int e = ks * 32 + quad * 8 + j;
        float v = x[((size_t)b * EMB + e) * CODES + (size_t)(cw + mt * 16 + col)] * 16384.f;
        float hf = hi_part(v);
        hv[j] = bf16_hi(v);
        lv[j] = bf16_hi(v - hf);
      }
      ah[mt][ks] = hv;
      al[mt][ks] = lv;
    }
  }

  // key = (u32)acc << 10 | (1023 - n); larger (1023-n) wins ties => earliest idx.
  u32 k1[2][4], k2[2][4];
  #pragma unroll
  for (int mt = 0; mt < 2; ++mt)
    #pragma unroll
    for (int r = 0; r < 4; ++r) { k1[mt][r] = 0u; k2[mt][r] = 0u; }

  // 1-deep pipeline state: previous tile's summed acc + its inv.
  // Fake tile: aPrev=0 -> key <= 1023, below any real key (>= 2^30).
  f32x4 aPrev0 = (f32x4){0.f, 0.f, 0.f, 0.f};
  f32x4 aPrev1 = (f32x4){0.f, 0.f, 0.f, 0.f};
  u32 invCur = 1023u - (u32)col;
  u32 invPrev = 0u;

  __syncthreads();   // drains epoch-0 staging (vmcnt) + wsh2 LDS

  for (int c = 0; c < EPOCHS; ++c) {
    if (c < EPOCHS - 1) {                          // async-stage next epoch
      const char* g = wsE + (size_t)(c + 1) * (CHUNK * 4096) + wave * 4096 + lane * 16;
      char* lb = smem + ((c + 1) & 1) * (CHUNK * 4096) + wave * 4096;
      async_copy16(g,        lb);
      async_copy16(g + 1024, lb + 1024);
      async_copy16(g + 2048, lb + 2048);
      async_copy16(g + 3072, lb + 3072);
    }

    // C-init scalars for this epoch, pinned BEFORE the asm pipeline so the
    // compiler's lgkmcnt wait for them cannot land inside the counted region.
    const float ch0 = lh[(c * CHUNK + 0) * 16 + col];
    const float ch1 = lh[(c * CHUNK + 1) * 16 + col];
    const float ch2 = lh[(c * CHUNK + 2) * 16 + col];
    const float ch3 = lh[(c * CHUNK + 3) * 16 + col];
    const float ch4 = lh[(c * CHUNK + 4) * 16 + col];
    const float ch5 = lh[(c * CHUNK + 5) * 16 + col];
    const float ch6 = lh[(c * CHUNK + 6) * 16 + col];
    const float ch7 = lh[(c * CHUNK + 7) * 16 + col];
    asm volatile("" :: "v"(ch0), "v"(ch1), "v"(ch2), "v"(ch3),
                       "v"(ch4), "v"(ch5), "v"(ch6), "v"(ch7));

    const unsigned base =
        (unsigned)(unsigned long long)(smem) +
        (unsigned)((c & 1) * (CHUNK * 4096)) + (unsigned)(lane * 16);

    i32x4 tA0, tA1, tA2, tA3, tB0, tB1, tB2, tB3;
    DS_READ_TILE(tA0, tA1, tA2, tA3, base, 0);     // prologue: tile 0 in flight

    DS_READ_TILE(tB0, tB1, tB2, tB3, base, 1);     // iter 0
    WAIT_SB(4);
    TILE_MATH(tA0, tA1, tA2, tA3, ch0);

    DS_READ_TILE(tA0, tA1, tA2, tA3, base, 2);     // iter 1
    WAIT_SB(4);
    TILE_MATH(tB0, tB1, tB2, tB3, ch1);

    DS_READ_TILE(tB0, tB1, tB2, tB3, base, 3);     // iter 2
    WAIT_SB(4);
    TILE_MATH(tA0, tA1, tA2, tA3, ch2);

    DS_READ_TILE(tA0, tA1, tA2, tA3, base, 4);     // iter 3
    WAIT_SB(4);
    TILE_MATH(tB0, tB1, tB2, tB3, ch3);

    DS_READ_TILE(tB0, tB1, tB2, tB3, base, 5);     // iter 4
    WAIT_SB(4);
    TILE_MATH(tA0, tA1, tA2, tA3, ch4);

    DS_READ_TILE(tA0, tA1, tA2, tA3, base, 6);     // iter 5
    WAIT_SB(4);
    TILE_MATH(tB0, tB1, tB2, tB3, ch5);

    DS_READ_TILE(tB0, tB1, tB2, tB3, base, 7);     // iter 6
    WAIT_SB(4);
    TILE_MATH(tA0, tA1, tA2, tA3, ch6);

    WAIT_SB(0);                                     // iter 7 (no issue)
    TILE_MATH(tB0, tB1, tB2, tB3, ch7);

    __syncthreads();   // drains next-epoch staging; protects buffer reuse
  }

  // Drain: retire the last tile (tile 63) held in the pipeline registers.
  TOP2(aPrev0, 0);
  TOP2(aPrev1, 1);

  // Merge top-2 across the 16 col-lanes (xor 1,2,4,8 stays inside quad group).
  uint2* cand = (uint2*)smem;                      // staging LDS now free
  int* idxs = (int*)(smem + 2048);
  #pragma unroll
  for (int mt = 0; mt < 2; ++mt) {
    #pragma unroll
    for (int r = 0; r < 4; ++r) {
      u32 a1 = k1[mt][r], a2 = k2[mt][r];
      #pragma unroll
      for (int m = 1; m <= 8; m <<= 1) {
        u32 r1 = __shfl_xor(a1, m, 64);
        u32 r2 = __shfl_xor(a2, m, 64);
        u32 t = a1 < r1 ? a1 : r1;
        a1 = umax_(a1, r1);
        a2 = umax_(umax_(a2, r2), t);
      }
      // C/D layout: local query = wave*32 + mt*16 + quad*4 + r
      if (col == r) cand[wave * 32 + mt * 16 + quad * 4 + r] = make_uint2(a1, a2);
    }
  }
  __syncthreads();

  // Rescore: all 512 threads; 2 threads/query (one candidate each), exact fp32.
  {
    const int q = tid >> 1, which = tid & 1;
    const u32 K = which ? cand[q].y : cand[q].x;
    const int i = 1023 - (int)(K & 1023u);
    const float* xq = x + (size_t)b * EMB * CODES + (size_t)(c0 + q);
    const float4* ei = (const float4*)(E + i * EMB);
    float d0 = 0, d1 = 0, d2 = 0, d3 = 0;
    #pragma unroll
    for (int g = 0; g < 16; ++g) {
      float4 a = ei[g];
      d0 = fmaf(xq[(size_t)(4 * g + 0) * CODES], a.x, d0);
      d1 = fmaf(xq[(size_t)(4 * g + 1) * CODES], a.y, d1);
      d2 = fmaf(xq[(size_t)(4 * g + 2) * CODES], a.z, d2);
      d3 = fmaf(xq[(size_t)(4 * g + 3) * CODES], a.w, d3);
    }
    const float s = ((d0 + d1) + (d2 + d3)) + wsh[i];
    const float s_o = __shfl_xor(s, 1, 64);
    const int i_o = __shfl_xor(i, 1, 64);
    if (which == 0) {
      // (s,i) = candidate 1; (s_o,i_o) = candidate 2
      const bool take2 = (s_o > s) || (s_o == s && i_o < i);
      const int idx = take2 ? i_o : i;
      idxs[q] = idx;
      iout[(size_t)b * CODES + (size_t)(c0 + q)] = (float)idx;
    }
  }
  __syncthreads();

  // Output fan-out: all 512 threads; thread -> (query = tid&255, e-half = tid>>8).
  {
    const int q = tid & (QPB - 1);
    const int eh = (tid >> 8) * 32;
    const int idx = idxs[q];
    const float* Er = E + idx * EMB + eh;
    float* xo = xout + ((size_t)b * EMB + eh) * CODES + (size_t)(c0 + q);
    #pragma unroll
    for (int e = 0; e < 32; ++e) xo[(size_t)e * CODES] = Er[e];
  }
}

extern "C" void kernel_launch(void* const* d_in, const int* in_sizes, int n_in,
                              void* d_out, int out_size, void* d_ws, size_t ws_size,
                              hipStream_t stream) {
  const float* x = (const float*)d_in[0];   // [16, 64, 16384]
  const float* E = (const float*)d_in[1];   // [1024, 64]
  float* xout = (float*)d_out;
  float* iout = (float*)d_out + (size_t)BB * EMB * CODES;

  char* wsE  = (char*)d_ws + WSE_OFF;
  float* wsh  = (float*)((char*)d_ws + WSH_OFF);
  float* wsh2 = (float*)((char*)d_ws + WSH2_OFF);

  vq_prep<<<36, 256, 0, stream>>>(E, wsE, wsh, wsh2);
  vq_main<<<dim3(CODES / QPB, BB), 512, 0, stream>>>(x, E, wsE, wsh, wsh2, xout, iout);
}